// Round 9
// baseline (117.393 us; speedup 1.0000x reference)
//
#include <hip/hip_runtime.h>
#include <math.h>

#define NROWS 8192
#define BHALF 4096
#define DDIM  128
#define NSPLIT 16
#define COLS_PER_BLOCK (NROWS / NSPLIT)   // 512
#define CHUNK 32                          // cols staged per LDS chunk
#define NCHUNK (COLS_PER_BLOCK / CHUNK)   // 16

typedef __bf16 bf16;
typedef __bf16 bf16x2 __attribute__((ext_vector_type(2)));
typedef __bf16 bf16x8 __attribute__((ext_vector_type(8)));
typedef float  f32x4  __attribute__((ext_vector_type(4)));
typedef float  f32x16 __attribute__((ext_vector_type(16)));

#define MFMA32(acc, va, vb) \
    acc = __builtin_amdgcn_mfma_f32_32x32x16_bf16(va, vb, acc, 0, 0, 0)

// opaque redefinition: forbids rematerialization of the fragment from memory
#define PIN4(x) asm volatile("" : "+v"(((float*)&(x))[0]), "+v"(((float*)&(x))[1]), \
                                  "+v"(((float*)&(x))[2]), "+v"(((float*)&(x))[3]))

#define C2F 2.8853900817779268f   // 2*log2(e)
#define SCF 1.6986433053702937f   // sqrt(2*log2(e))

// ---------------------------------------------------------------------------
// Kernel 1: L2-normalize, scale by sqrt(2*log2(e)), split fp32 -> bf16 hi+lo.
// ---------------------------------------------------------------------------
__global__ __launch_bounds__(256) void nt_prep(const float* __restrict__ zis,
                                               const float* __restrict__ zjs,
                                               bf16* __restrict__ rhi,
                                               bf16* __restrict__ rlo) {
    int row  = blockIdx.x * 4 + (threadIdx.x >> 6);
    int lane = threadIdx.x & 63;
    const float* src = (row < BHALF) ? (zis + (size_t)row * DDIM)
                                     : (zjs + (size_t)(row - BHALF) * DDIM);
    float2 v = ((const float2*)src)[lane];
    float ss = v.x * v.x + v.y * v.y;
    #pragma unroll
    for (int off = 1; off < 64; off <<= 1) ss += __shfl_xor(ss, off);
    float invs = SCF / fmaxf(sqrtf(ss), 1e-12f);
    float y0 = v.x * invs, y1 = v.y * invs;
    bf16 h0 = (bf16)y0, h1 = (bf16)y1;
    bf16 l0 = (bf16)(y0 - (float)h0), l1 = (bf16)(y1 - (float)h1);
    bf16x2 hv, lv;
    hv[0] = h0; hv[1] = h1; lv[0] = l0; lv[1] = l1;
    *(bf16x2*)(rhi + (size_t)row * DDIM + 2 * lane) = hv;
    *(bf16x2*)(rlo + (size_t)row * DDIM + 2 * lane) = lv;
}

// ---------------------------------------------------------------------------
// Kernel 2: sim GEMM via 32x32x16 MFMA (3-pass split-bf16) + fused exp2 sum.
// 256 thr / 4 waves; each wave owns 32 rows (frags pinned in VGPRs: 64 regs).
// Per chunk (32 cols): each wave reads 16 b128 from LDS -> 24 MFMA -> 16 exp2.
// LDS-read traffic is HALF of R8 (operand reuse doubled); 4-bit XOR swizzle.
// C/D map (m74/m101): i = lane&31, j = (reg&3) + 8*(reg>>2) + 4*(lane>>5).
// ---------------------------------------------------------------------------
__global__ __launch_bounds__(256) void nt_sim(const bf16* __restrict__ rhi,
                                              const bf16* __restrict__ rlo,
                                              float* __restrict__ partial,
                                              float* __restrict__ posA) {
    // LDS: 2 buffers x (hi 8KB + lo 8KB) = 32 KB
    __shared__ __align__(16) char smem[32768];

    const int tid  = threadIdx.x;
    const int lane = tid & 63;
    const int w    = tid >> 6;      // wave 0..3
    const int ci   = lane & 31;     // this lane's row slot (C/D col)
    const int h    = lane >> 5;     // 0/1: k-half for A/B frags

    const int i0 = blockIdx.x * 128;              // block row base
    const int j0 = blockIdx.y * COLS_PER_BLOCK;   // block col base
    const bool capture = (blockIdx.y == (unsigned)((i0 ^ BHALF) >> 9));

    const int myrow = i0 + w * 32 + ci;

    // ---- row fragments (B operand): lane holds rep[myrow][kk*16 + h*8 + e].
    // 8 frags x 4 VGPR x (hi,lo) = 64 regs, pinned against remat (R7 lesson).
    f32x4 rhv[8], rlv[8];
    #pragma unroll
    for (int kk = 0; kk < 8; ++kk) {
        rhv[kk] = *(const f32x4*)(rhi + (size_t)myrow * DDIM + kk * 16 + h * 8);
        rlv[kk] = *(const f32x4*)(rlo + (size_t)myrow * DDIM + kk * 16 + h * 8);
        PIN4(rhv[kk]);
        PIN4(rlv[kk]);
    }

    float s = 0.0f;

    for (int c = 0; c <= NCHUNK; ++c) {
        // ---- stage chunk c into buffer c&1 ----
        // LDS layout per region: col*256B + slot*16B, slot = linear ^ (col&15).
        // gload_lds dst is linear (uniform base + lane*16); source slot is
        // inverse-permuted (same involution) per rule: both-sides-or-neither.
        if (c < NCHUNK) {
            char* dstb = smem + (c & 1) * 16384;
            const int colbase = j0 + c * CHUNK;
            #pragma unroll
            for (int p = 0; p < 2; ++p) {
                const int L   = p * 256 + tid;        // 0..511 16B-slots
                const int col = L >> 4, sl = L & 15;
                const size_t soff = (size_t)(colbase + col) * DDIM
                                  + ((sl ^ (col & 15)) << 3);
                __builtin_amdgcn_global_load_lds(
                    (const __attribute__((address_space(1))) void*)(rhi + soff),
                    (__attribute__((address_space(3))) void*)(dstb + L * 16),
                    16, 0, 0);
                __builtin_amdgcn_global_load_lds(
                    (const __attribute__((address_space(1))) void*)(rlo + soff),
                    (__attribute__((address_space(3))) void*)(dstb + 8192 + L * 16),
                    16, 0, 0);
            }
        }
        if (c == 0) { __syncthreads(); continue; }

        // ---- compute chunk c-1: one 32x32 tile, K=128, 3 passes = 24 MFMA ----
        const char* bh = smem + ((c - 1) & 1) * 16384;
        const char* bl = bh + 8192;
        const int cc = c - 1;

        f32x16 a;
        #pragma unroll
        for (int r = 0; r < 16; ++r) a[r] = -C2F;

        #pragma unroll
        for (int kk = 0; kk < 8; ++kk) {
            const int off = ci * 256 + (((((kk << 1) | h)) ^ (ci & 15)) << 4);
            bf16x8 ch = *(const bf16x8*)(bh + off);
            bf16x8 cl = *(const bf16x8*)(bl + off);
            MFMA32(a, ch, __builtin_bit_cast(bf16x8, rhv[kk]));
            MFMA32(a, ch, __builtin_bit_cast(bf16x8, rlv[kk]));
            MFMA32(a, cl, __builtin_bit_cast(bf16x8, rhv[kk]));
        }

        // epilogue: s += sum_r exp2(a[r])   (no mask; diag term==1 subtracted later)
        float e = 0.0f;
        #pragma unroll
        for (int r = 0; r < 16; ++r) e += exp2f(a[r]);
        s += e;

        // positive-pair logit capture (wave-uniform skip in 15/16 blocks)
        if (capture) {
            const int rel = (myrow ^ BHALF) - (j0 + cc * CHUNK);
            if (rel >= 0 && rel < 32 && ((rel >> 2) & 1) == h) {
                const int b = rel & 3;      // = reg & 3
                const int g = rel >> 3;     // = reg >> 2
                float x0 = (b & 1) ? a[1]  : a[0];
                float x1 = (b & 1) ? a[3]  : a[2];
                float x2 = (b & 1) ? a[5]  : a[4];
                float x3 = (b & 1) ? a[7]  : a[6];
                float x4 = (b & 1) ? a[9]  : a[8];
                float x5 = (b & 1) ? a[11] : a[10];
                float x6 = (b & 1) ? a[13] : a[12];
                float x7 = (b & 1) ? a[15] : a[14];
                float y0 = (b & 2) ? x1 : x0;   // g=0
                float y1 = (b & 2) ? x3 : x2;   // g=1
                float y2 = (b & 2) ? x5 : x4;   // g=2
                float y3 = (b & 2) ? x7 : x6;   // g=3
                float z0 = (g & 1) ? y1 : y0;
                float z1 = (g & 1) ? y3 : y2;
                posA[myrow] = (g & 2) ? z1 : z0;
            }
        }
        __syncthreads();
    }

    // ---- per-row total: merge the two k-halves (lanes l and l+32 share row) ----
    s += __shfl_xor(s, 32);
    if (lane < 32) partial[(size_t)blockIdx.y * NROWS + myrow] = s;
}

// ---------------------------------------------------------------------------
// Kernel 3: merge partials, lse = 2 + log(sum - 1), pos = 2*(a+C2)/C2,
// mean over rows. 8 blocks + one atomicAdd each (out pre-zeroed by memset).
// ---------------------------------------------------------------------------
__global__ __launch_bounds__(1024) void nt_final(const float* __restrict__ partial,
                                                 const float* __restrict__ posA,
                                                 float* __restrict__ out) {
    int i = blockIdx.x * 1024 + threadIdx.x;
    float ssum = 0.0f;
    #pragma unroll
    for (int p = 0; p < NSPLIT; ++p) ssum += partial[(size_t)p * NROWS + i];
    float a = posA[i];                        // C2*dot_pos - C2
    float acc = 2.0f + logf(ssum - 1.0f) - 2.0f * (a + C2F) / C2F;

    #pragma unroll
    for (int off = 1; off < 64; off <<= 1) acc += __shfl_xor(acc, off);
    __shared__ float wsum[16];
    int tid = threadIdx.x;
    if ((tid & 63) == 0) wsum[tid >> 6] = acc;
    __syncthreads();
    if (tid == 0) {
        float t = 0.0f;
        #pragma unroll
        for (int k = 0; k < 16; ++k) t += wsum[k];
        atomicAdd(out, t * (1.0f / (float)NROWS));
    }
}

// ---------------------------------------------------------------------------
extern "C" void kernel_launch(void* const* d_in, const int* in_sizes, int n_in,
                              void* d_out, int out_size, void* d_ws, size_t ws_size,
                              hipStream_t stream) {
    const float* zis = (const float*)d_in[0];
    const float* zjs = (const float*)d_in[1];
    float* out = (float*)d_out;

    char* ws = (char*)d_ws;
    bf16*  rhi     = (bf16*)ws;                                   // 2 MB
    bf16*  rlo     = (bf16*)(ws + (size_t)NROWS * DDIM * 2);      // 2 MB
    float* partial = (float*)(ws + (size_t)NROWS * DDIM * 4);     // 512 KB
    float* posA    = (float*)(ws + (size_t)NROWS * DDIM * 4
                                 + (size_t)NSPLIT * NROWS * 4);   // 32 KB

    hipMemsetAsync(out, 0, sizeof(float), stream);
    nt_prep <<<NROWS / 4, 256, 0, stream>>>(zis, zjs, rhi, rlo);
    nt_sim  <<<dim3(NROWS / 128, NSPLIT), 256, 0, stream>>>(rhi, rlo, partial, posA);
    nt_final<<<NROWS / 1024, 1024, 0, stream>>>(partial, posA, out);
}